// Round 18
// baseline (717.799 us; speedup 1.0000x reference)
//
#include <hip/hip_runtime.h>
#include <hip/hip_bf16.h>
#include <stdint.h>

typedef __bf16 bf16_t;
typedef __bf16 bf16x8 __attribute__((ext_vector_type(8)));
typedef float  f32x4  __attribute__((ext_vector_type(4)));

#define DEV __device__ __forceinline__

constexpr int   Bn = 2, Tn = 2048, Dn = 2048, Hn = 16, DHn = 128;
constexpr int   BTn = Bn * Tn;          // 4096 rows
constexpr int   TD3 = 3 * Dn;           // 6144
constexpr int   FGn = 5461, FGPn = 5504; // pad to 43*128 (688 blocks, %8==0)
constexpr float EPSf   = 1e-5f;
constexpr float LOG2E  = 1.4426950408889634f;
constexpr float ASCALE = 0.08838834764831845f;   // 1/sqrt(128)
constexpr float LN1E4  = 9.210340371976184f;     // ln(10000)

// async global->LDS, 16B per lane, wave-uniform LDS base (HW adds lane*16)
DEV void gld16(void* lds, const void* g) {
  __builtin_amdgcn_global_load_lds(
      (__attribute__((address_space(1))) void*)(void*)g,
      (__attribute__((address_space(3))) void*)lds, 16, 0, 0);
}

// inline-asm LDS read, ordered only by explicit s_waitcnt lgkmcnt(N)
DEV bf16x8 dsr128(const bf16_t* p) {
  bf16x8 r;
  asm volatile("ds_read_b128 %0, %1"
               : "=v"(r)
               : "v"((const __attribute__((address_space(3))) bf16_t*)p));
  return r;
}

// ---------------- RMSNorm (fp32 in -> bf16 out) ----------------
__global__ __launch_bounds__(256)
void rmsnorm_k(const float* __restrict__ x, const float* __restrict__ w,
               bf16_t* __restrict__ out) {
  const int row = blockIdx.x;
  const int tid = threadIdx.x;
  const float* xr = x + (size_t)row * Dn;
  float4 a = ((const float4*)xr)[tid * 2];
  float4 b = ((const float4*)xr)[tid * 2 + 1];
  float ss = a.x*a.x + a.y*a.y + a.z*a.z + a.w*a.w
           + b.x*b.x + b.y*b.y + b.z*b.z + b.w*b.w;
#pragma unroll
  for (int off = 32; off > 0; off >>= 1) ss += __shfl_xor(ss, off, 64);
  __shared__ float red[4];
  if ((tid & 63) == 0) red[tid >> 6] = ss;
  __syncthreads();
  float tot = red[0] + red[1] + red[2] + red[3];
  float rms = rsqrtf(tot * (1.0f / Dn) + EPSf);
  float4 wa = ((const float4*)w)[tid * 2];
  float4 wb = ((const float4*)w)[tid * 2 + 1];
  bf16x8 o;
  o[0] = (bf16_t)(a.x * rms * wa.x); o[1] = (bf16_t)(a.y * rms * wa.y);
  o[2] = (bf16_t)(a.z * rms * wa.z); o[3] = (bf16_t)(a.w * rms * wa.w);
  o[4] = (bf16_t)(b.x * rms * wb.x); o[5] = (bf16_t)(b.y * rms * wb.y);
  o[6] = (bf16_t)(b.z * rms * wb.z); o[7] = (bf16_t)(b.w * rms * wb.w);
  *(bf16x8*)&out[(size_t)row * Dn + tid * 8] = o;
}

// ------- fused: x1 = x + P0 + P1 (fp32 out) ; h = rmsnorm(x1)*w (bf16) ----
__global__ __launch_bounds__(256)
void rms_fused(const float* __restrict__ x, const bf16_t* __restrict__ P0,
               const bf16_t* __restrict__ P1, const float* __restrict__ w,
               float* __restrict__ out, bf16_t* __restrict__ h) {
  const int row = blockIdx.x;
  const int tid = threadIdx.x;
  const size_t base = (size_t)row * Dn + tid * 8;
  float4 a = ((const float4*)(x + base))[0];
  float4 b = ((const float4*)(x + base))[1];
  bf16x8 p0 = *(const bf16x8*)&P0[base];
  bf16x8 p1 = *(const bf16x8*)&P1[base];
  float v[8];
  v[0] = a.x + (float)p0[0] + (float)p1[0];
  v[1] = a.y + (float)p0[1] + (float)p1[1];
  v[2] = a.z + (float)p0[2] + (float)p1[2];
  v[3] = a.w + (float)p0[3] + (float)p1[3];
  v[4] = b.x + (float)p0[4] + (float)p1[4];
  v[5] = b.y + (float)p0[5] + (float)p1[5];
  v[6] = b.z + (float)p0[6] + (float)p1[6];
  v[7] = b.w + (float)p0[7] + (float)p1[7];
  float4 o0 = {v[0], v[1], v[2], v[3]};
  float4 o1 = {v[4], v[5], v[6], v[7]};
  ((float4*)(out + base))[0] = o0;
  ((float4*)(out + base))[1] = o1;
  float ss = 0.f;
#pragma unroll
  for (int k = 0; k < 8; ++k) ss += v[k] * v[k];
#pragma unroll
  for (int off = 32; off > 0; off >>= 1) ss += __shfl_xor(ss, off, 64);
  __shared__ float red[4];
  if ((tid & 63) == 0) red[tid >> 6] = ss;
  __syncthreads();
  float tot = red[0] + red[1] + red[2] + red[3];
  float rms = rsqrtf(tot * (1.0f / Dn) + EPSf);
  float4 wa = ((const float4*)w)[tid * 2];
  float4 wb = ((const float4*)w)[tid * 2 + 1];
  bf16x8 o;
  o[0] = (bf16_t)(v[0] * rms * wa.x); o[1] = (bf16_t)(v[1] * rms * wa.y);
  o[2] = (bf16_t)(v[2] * rms * wa.z); o[3] = (bf16_t)(v[3] * rms * wa.w);
  o[4] = (bf16_t)(v[4] * rms * wb.x); o[5] = (bf16_t)(v[5] * rms * wb.y);
  o[6] = (bf16_t)(v[6] * rms * wb.z); o[7] = (bf16_t)(v[7] * rms * wb.w);
  *(bf16x8*)&h[base] = o;
}

// ---------------- fp32 -> bf16 convert with zero padding ----------------
__global__ __launch_bounds__(256)
void cvt_pad_k(const float* __restrict__ src, bf16_t* __restrict__ dst,
               int srcR, int srcC, int dstC, int n8) {
  int i = blockIdx.x * 256 + threadIdx.x;
  if (i >= n8) return;
  long base = (long)i * 8;
  int r = (int)(base / dstC);
  int c = (int)(base % dstC);
  bf16x8 o;
#pragma unroll
  for (int k = 0; k < 8; ++k) {
    int cc = c + k;
    float v = (r < srcR && cc < srcC) ? src[(size_t)r * srcC + cc] : 0.0f;
    o[k] = (bf16_t)v;
  }
  *(bf16x8*)&dst[base] = o;
}

// ------------- reduce: out += P0 + P1 (mlp epilogue) ---------------------
__global__ __launch_bounds__(256)
void reduce_k(float* __restrict__ out, const bf16_t* __restrict__ P0,
              const bf16_t* __restrict__ P1) {
  int i = blockIdx.x * 256 + threadIdx.x;
  bf16x8 p0 = *(const bf16x8*)&P0[(size_t)i * 8];
  bf16x8 p1 = *(const bf16x8*)&P1[(size_t)i * 8];
  float4 o0 = ((const float4*)out)[i * 2];
  float4 o1 = ((const float4*)out)[i * 2 + 1];
  o0.x += (float)p0[0] + (float)p1[0];
  o0.y += (float)p0[1] + (float)p1[1];
  o0.z += (float)p0[2] + (float)p1[2];
  o0.w += (float)p0[3] + (float)p1[3];
  o1.x += (float)p0[4] + (float)p1[4];
  o1.y += (float)p0[5] + (float)p1[5];
  o1.z += (float)p0[6] + (float)p1[6];
  o1.w += (float)p0[7] + (float)p1[7];
  ((float4*)out)[i * 2]     = o0;
  ((float4*)out)[i * 2 + 1] = o1;
}

// -------- split-K=2 GEMM, BK=64 2-slot (best measured: ~5860 cyc/K64) ----
__global__ __launch_bounds__(512, 2)
void gemm_sk(const bf16_t* __restrict__ A, const bf16_t* __restrict__ W,
             bf16_t* __restrict__ P0, bf16_t* __restrict__ P1,
             int ldk, int klen, int ldc, int nby) {
  __shared__ __align__(128) bf16_t As[2][256 * 64];   // 2 x 32KB
  __shared__ __align__(128) bf16_t Bs[2][256 * 64];   // 2 x 32KB
  const int tid = threadIdx.x;
  const int lane = tid & 63, w = tid >> 6;
  const int wm = w >> 2, wn = w & 3;
  const int g = lane >> 4, q = lane & 15;

  const int nwg = gridDim.x;               // % 8 == 0
  const int cpx = nwg >> 3;
  const int nid = (blockIdx.x & 7) * cpx + (blockIdx.x >> 3);
  const int half = nwg >> 1;
  const int s   = nid / half;
  const int rem = nid % half;
  const int bx = rem / nby, by = rem % nby;
  const int row0 = by * 256, col0 = bx * 256;
  const int kofs = s * klen;
  bf16_t* P = s ? P1 : P0;

  f32x4 acc[8][4] = {};

  const bf16_t* Asrc[4];
  const bf16_t* Wsrc[4];
  int aoff[4];
#pragma unroll
  for (int i = 0; i < 4; ++i) {
    int ci = i * 512 + tid;
    int r  = ci >> 3;
    int cs = (ci & 7) ^ (r & 7);
    Asrc[i] = A + (size_t)(row0 + r) * ldk + kofs + cs * 8;
    Wsrc[i] = W + (size_t)(col0 + r) * ldk + kofs + cs * 8;
    aoff[i] = i * 8192 + w * 1024;
  }

  int offA[2][8], offB[2][4];
#pragma unroll
  for (int kk = 0; kk < 2; ++kk) {
#pragma unroll
    for (int m = 0; m < 8; ++m) {
      int r = wm * 128 + m * 16 + q;
      offA[kk][m] = r * 128 + (((kk * 4 + g) ^ (r & 7)) * 16);
    }
#pragma unroll
    for (int n = 0; n < 4; ++n) {
      int r = wn * 64 + n * 16 + q;
      offB[kk][n] = r * 128 + (((kk * 4 + g) ^ (r & 7)) * 16);
    }
  }

  const int NT = klen >> 6;
  auto stage = [&](int T, int h) {
    const int slot = T & 1;
    const size_t kk = (size_t)T * 64;
#pragma unroll
    for (int i = 0; i < 2; ++i) {
      int rd = h * 2 + i;
      gld16((char*)As[slot] + aoff[rd], Asrc[rd] + kk);
      gld16((char*)Bs[slot] + aoff[rd], Wsrc[rd] + kk);
    }
  };

  bf16x8 af[8], bfr[4];

  auto half_rd = [&](const char* as_, const char* bs_, int kk) {
#pragma unroll
    for (int m = 0; m < 8; ++m) af[m] = dsr128((const bf16_t*)(as_ + offA[kk][m]));
#pragma unroll
    for (int n = 0; n < 4; ++n) bfr[n] = dsr128((const bf16_t*)(bs_ + offB[kk][n]));
  };
  auto mfmas = [&]() {
    asm volatile("s_waitcnt lgkmcnt(0)" ::: "memory");
    __builtin_amdgcn_sched_barrier(0);
    __builtin_amdgcn_s_setprio(1);
#pragma unroll
    for (int m = 0; m < 8; ++m)
#pragma unroll
      for (int n = 0; n < 4; ++n)
        acc[m][n] = __builtin_amdgcn_mfma_f32_16x16x32_bf16(af[m], bfr[n], acc[m][n], 0, 0, 0);
    __builtin_amdgcn_s_setprio(0);
    __builtin_amdgcn_sched_barrier(0);
  };

  stage(0, 0); stage(0, 1);
  asm volatile("s_waitcnt vmcnt(0)" ::: "memory");
  asm volatile("s_barrier" ::: "memory");

  for (int T = 0; T < NT; ++T) {
    const char* as_ = (const char*)As[T & 1];
    const char* bs_ = (const char*)Bs[T & 1];
    const bool st = (T + 1 < NT);
    half_rd(as_, bs_, 0);
    if (st) stage(T + 1, 0);
    mfmas();
    half_rd(as_, bs_, 1);
    if (st) stage(T + 1, 1);
    mfmas();
    if (st) asm volatile("s_waitcnt vmcnt(0)" ::: "memory");
    asm volatile("s_barrier" ::: "memory");
  }

#pragma unroll
  for (int m = 0; m < 8; ++m)
#pragma unroll
    for (int n = 0; n < 4; ++n)
#pragma unroll
      for (int j = 0; j < 4; ++j) {
        int r = row0 + wm * 128 + m * 16 + g * 4 + j;
        int c = col0 + wn * 64 + n * 16 + q;
        P[(size_t)r * ldc + c] = (bf16_t)acc[m][n][j];
      }
}

// ------- fused gate+val dual GEMM, BK=64, fp32-weight direct staging -----
// Out = silu(A Wg^T) * (A Wv^T); Wg/Wv are UNPADDED fp32 (FGn x Dn).
// B-path: fp32 loads for tile T+1 issued at step-T START (~5800cyc cover),
// cvt + per-lane ds_write at step-T END (boff includes tid*16 — R17 bug was
// a wave-uniform offset valid only for global_load_lds), lgkmcnt(0) before
// the publish barrier. A-path unchanged. Rows >= FGn zero-filled.
__global__ __launch_bounds__(512, 2)
void gemmgv(const bf16_t* __restrict__ A, const float* __restrict__ Wg,
            const float* __restrict__ Wv, bf16_t* __restrict__ Out,
            int K, int ldc, int nby) {
  __shared__ __align__(128) bf16_t As[2][256 * 64];   // 2 x 32KB
  __shared__ __align__(128) bf16_t Gs[2][128 * 64];   // 2 x 16KB
  __shared__ __align__(128) bf16_t Vs[2][128 * 64];   // 2 x 16KB
  const int tid = threadIdx.x;
  const int lane = tid & 63, w = tid >> 6;
  const int wm = w >> 2, wn = w & 3;
  const int g = lane >> 4, q = lane & 15;

  const int nwg = gridDim.x;                 // 688, % 8 == 0
  const int cpx = nwg >> 3;
  const int nid = (blockIdx.x & 7) * cpx + (blockIdx.x >> 3);
  const int bx = nid / nby, by = nid % nby;
  const int row0 = by * 256, col0 = bx * 128;

  f32x4 accg[8][2] = {}, accv[8][2] = {};

  const bf16_t* Asrc[4];
  int aoff[4];
#pragma unroll
  for (int i = 0; i < 4; ++i) {
    int ci = i * 512 + tid;
    int r  = ci >> 3;
    int cs = (ci & 7) ^ (r & 7);
    Asrc[i] = A + (size_t)(row0 + r) * K + cs * 8;
    aoff[i] = i * 8192 + w * 1024;          // wave-uniform (gld16 adds lane*16)
  }
  // B fp32 sources: round i covers rows [64i, 64i+64) of the 128-row tile
  const float* Gsrc[2];
  const float* Vsrc[2];
  bool bvalid[2];
  int boff[2];
#pragma unroll
  for (int i = 0; i < 2; ++i) {
    int ci = i * 512 + tid;
    int r  = ci >> 3;
    int cs = (ci & 7) ^ (r & 7);
    int rg = col0 + r;
    bvalid[i] = (rg < FGn);
    const size_t rb = (size_t)(bvalid[i] ? rg : 0) * K + cs * 8;
    Gsrc[i] = Wg + rb;
    Vsrc[i] = Wv + rb;
    boff[i] = i * 8192 + tid * 16;          // PER-LANE byte offset (ds_write)
  }

  int offA[2][8], offB[2][2];
#pragma unroll
  for (int kk = 0; kk < 2; ++kk) {
#pragma unroll
    for (int m = 0; m < 8; ++m) {
      int r = wm * 128 + m * 16 + q;
      offA[kk][m] = r * 128 + (((kk * 4 + g) ^ (r & 7)) * 16);
    }
#pragma unroll
    for (int n = 0; n < 2; ++n) {
      int r = wn * 32 + n * 16 + q;
      offB[kk][n] = r * 128 + (((kk * 4 + g) ^ (r & 7)) * 16);
    }
  }

  const int NT = K >> 6;                 // 32
  auto stageA = [&](int T, int h) {
    const int slot = T & 1;
    const size_t kk = (size_t)T * 64;
#pragma unroll
    for (int i = 0; i < 2; ++i) {
      int rd = h * 2 + i;
      gld16((char*)As[slot] + aoff[rd], Asrc[rd] + kk);
    }
  };

  f32x4 fG[2][2], fV[2][2];              // [round][pair of float4]
  auto ldB32 = [&](int T) {
    const size_t kk = (size_t)T * 64;
#pragma unroll
    for (int i = 0; i < 2; ++i) {
      if (bvalid[i]) {
        fG[i][0] = ((const f32x4*)(Gsrc[i] + kk))[0];
        fG[i][1] = ((const f32x4*)(Gsrc[i] + kk))[1];
        fV[i][0] = ((const f32x4*)(Vsrc[i] + kk))[0];
        fV[i][1] = ((const f32x4*)(Vsrc[i] + kk))[1];
      } else {
        fG[i][0] = f32x4{0,0,0,0}; fG[i][1] = f32x4{0,0,0,0};
        fV[i][0] = f32x4{0,0,0,0}; fV[i][1] = f32x4{0,0,0,0};
      }
    }
  };
  auto writeB = [&](int T) {
    const int slot = T & 1;
#pragma unroll
    for (int i = 0; i < 2; ++i) {
      bf16x8 og, ov;
#pragma unroll
      for (int k = 0; k < 4; ++k) {
        og[k]     = (bf16_t)fG[i][0][k];
        og[4 + k] = (bf16_t)fG[i][1][k];
        ov[k]     = (bf16_t)fV[i][0][k];
        ov[4 + k] = (bf16_t)fV[i][1][k];
      }
      *(bf16x8*)((char*)Gs[slot] + boff[i]) = og;
      *(bf16x8*)((char*)Vs[slot] + boff[i]) = ov;
    }
  };

  bf16x8 af[8], bg[2], bv[2];

  auto half_rd = [&](const char* as_, const char* gs_, const char* vs_, int kk) {
#pragma unroll
    for (int m = 0; m < 8; ++m) af[m] = dsr128((const bf16_t*)(as_ + offA[kk][m]));
#pragma unroll
    for (int n = 0; n < 2; ++n) {
      bg[n] = dsr128((const bf16_t*)(gs_ + offB[kk][n]));
      bv[n] = dsr128((const bf16_t*)(vs_ + offB[kk][n]));
    }
  };
  auto mfmas = [&]() {
    asm volatile("s_waitcnt lgkmcnt(0)" ::: "memory");
    __builtin_amdgcn_sched_barrier(0);
    __builtin_amdgcn_s_setprio(1);
#pragma unroll
    for (int m = 0; m < 8; ++m)
#pragma unroll
      for (int n = 0; n < 2; ++n) {
        accg[m][n] = __builtin_amdgcn_mfma_f32_16x16x32_bf16(af[m], bg[n], accg[m][n], 0, 0, 0);
        accv[m][n] = __builtin_amdgcn_mfma_f32_16x16x32_bf16(af[m], bv[n], accv[m][n], 0, 0, 0);
      }
    __builtin_amdgcn_s_setprio(0);
    __builtin_amdgcn_sched_barrier(0);
  };

  // prologue: tile 0 -> LDS (A via gld16; B via fp32 reg-convert)
  ldB32(0);
  stageA(0, 0); stageA(0, 1);
  writeB(0);                                       // waits own fp32 loads
  asm volatile("s_waitcnt lgkmcnt(0)" ::: "memory"); // B writes landed
  asm volatile("s_waitcnt vmcnt(0)" ::: "memory");   // A glds landed
  asm volatile("s_barrier" ::: "memory");

  for (int T = 0; T < NT; ++T) {
    const char* as_ = (const char*)As[T & 1];
    const char* gs_ = (const char*)Gs[T & 1];
    const char* vs_ = (const char*)Vs[T & 1];
    const bool st = (T + 1 < NT);
    if (st) ldB32(T + 1);               // issue early: lands under this step
    half_rd(as_, gs_, vs_, 0);
    if (st) stageA(T + 1, 0);
    mfmas();
    half_rd(as_, gs_, vs_, 1);
    if (st) stageA(T + 1, 1);
    mfmas();
    if (st) {
      writeB(T + 1);                    // cvt + 4 LDS stores (slot T+1)
      asm volatile("s_waitcnt lgkmcnt(0)" ::: "memory");  // stores landed
      asm volatile("s_waitcnt vmcnt(0)" ::: "memory");    // A glds landed
    }
    asm volatile("s_barrier" ::: "memory");
  }

#pragma unroll
  for (int m = 0; m < 8; ++m) {
#pragma unroll
    for (int n = 0; n < 2; ++n) {
#pragma unroll
      for (int j = 0; j < 4; ++j) {
        int r = row0 + wm * 128 + m * 16 + g * 4 + j;
        int c = col0 + wn * 32 + n * 16 + q;
        float gt = accg[m][n][j];
        float sg = gt / (1.0f + __expf(-gt));
        Out[(size_t)r * ldc + c] = (bf16_t)(sg * accv[m][n][j]);
      }
    }
  }
}

// -------- fused RoPE: reads qkv split-K partials (P0+P1), split + V^T ----
__global__ __launch_bounds__(256)
void rope_fused(const bf16_t* __restrict__ P0, const bf16_t* __restrict__ P1,
                bf16_t* __restrict__ Qb, bf16_t* __restrict__ Kb,
                bf16_t* __restrict__ Vt) {
  const int t0 = blockIdx.x * 32;
  const int bh = blockIdx.y;
  const int b = bh >> 4, hh = bh & 15;
  __shared__ bf16_t Vl[32][132];

#pragma unroll
  for (int it = 0; it < 2; ++it) {
    int task = threadIdx.x + it * 256;
    int tt = task >> 4, ck = task & 15, d0 = ck * 8;
    int tg = t0 + tt;
    const size_t rb = (size_t)(b * Tn + tg) * TD3 + hh * DHn + d0;
    bf16x8 q0 = *(const bf16x8*)&P0[rb];
    bf16x8 q1 = *(const bf16x8*)&P1[rb];
    bf16x8 k0 = *(const bf16x8*)&P0[rb + Dn];
    bf16x8 k1 = *(const bf16x8*)&P1[rb + Dn];
    bf16x8 v0 = *(const bf16x8*)&P0[rb + 2 * Dn];
    bf16x8 v1 = *(const bf16x8*)&P1[rb + 2 * Dn];
    bf16x8 qo, ko, vo;
#pragma unroll
    for (int p = 0; p < 4; ++p) {
      int jj = (d0 >> 1) + p;
      float fr = __expf(-((float)(2 * jj) / 128.0f) * LN1E4);
      float ang = (float)tg * fr;
      float cs = cosf(ang), sn = sinf(ang);
      float qe = (float)q0[2 * p] + (float)q1[2 * p];
      float qod = (float)q0[2 * p + 1] + (float)q1[2 * p + 1];
      float ke = (float)k0[2 * p] + (float)k1[2 * p];
      float kod = (float)k0[2 * p + 1] + (float)k1[2 * p + 1];
      qo[2 * p]     = (bf16_t)((qe * cs - qod * sn) * ASCALE);
      qo[2 * p + 1] = (bf16_t)((qod * cs + qe * sn) * ASCALE);
      ko[2 * p]     = (bf16_t)(ke * cs - kod * sn);
      ko[2 * p + 1] = (bf16_t)(kod * cs + ke * sn);
      vo[2 * p]     = (bf16_t)((float)v0[2 * p] + (float)v1[2 * p]);
      vo[2 * p + 1] = (bf16_t)((float)v0[2 * p + 1] + (float)v1[2 * p + 1]);
    }
    *(bf16x8*)&Qb[((size_t)bh * Tn + tg) * DHn + d0] = qo;
    *(bf16x8*)&Kb[((size_t)bh * Tn + tg) * DHn + d0] = ko;
    *(bf16x8*)&Vl[tt][d0] = vo;
  }
  __syncthreads();
#pragma unroll
  for (int it = 0; it < 2; ++it) {
    int task = threadIdx.x + it * 256;
    int dd = task >> 2, tc = (task & 3) * 8;
    bf16x8 ov;
#pragma unroll
    for (int i = 0; i < 8; ++i) ov[i] = Vl[tc + i][dd];
    *(bf16x8*)&Vt[((size_t)bh * DHn + dd) * Tn + t0 + tc] = ov;
  }
}

// ---------------- causal flash attention, paired q-tiles ----------------
__global__ __launch_bounds__(256, 2)
void attn_k(const bf16_t* __restrict__ Qb, const bf16_t* __restrict__ Kb,
            const bf16_t* __restrict__ Vt, bf16_t* __restrict__ Y) {
  const int orig = blockIdx.x + 16 * blockIdx.y;   // 512 blocks total
  const int nid  = (orig & 7) * 64 + (orig >> 3);  // XCD-chunked, bijective
  const int pi = nid & 15;
  const int bh = nid >> 4;
  const int b = bh >> 4, hh = bh & 15;
  const int tid = threadIdx.x, lane = tid & 63, w = tid >> 6;
  const int g = lane >> 4, q = lane & 15;
  const int iA = pi, iB = 31 - pi;
  const int kmax = iB;

  __shared__ bf16_t Ks[2][64 * 128];
  __shared__ bf16_t Vs[2][128 * 64];
  __shared__ bf16_t Ps[4][16 * 72];

  bf16x8 aqA[4], aqB[4];
  {
    const bf16_t* QrA = Qb + ((size_t)bh * Tn + iA * 64 + w * 16 + q) * DHn;
    const bf16_t* QrB = Qb + ((size_t)bh * Tn + iB * 64 + w * 16 + q) * DHn;
#pragma unroll
    for (int s = 0; s < 4; ++s) {
      aqA[s] = *(const bf16x8*)(QrA + s * 32 + g * 8);
      aqB[s] = *(const bf16x8*)(QrB + s * 32 + g * 8);
    }
  }

  f32x4 oA[8] = {}, oB[8] = {};
  float mA[4], lA[4], mB[4], lB[4];
#pragma unroll
  for (int j = 0; j < 4; ++j) {
    mA[j] = -__builtin_inff(); lA[j] = 0.0f;
    mB[j] = -__builtin_inff(); lB[j] = 0.0f;
  }

  auto stage = [&](int buf, int kt) {
    const int k0 = kt * 64;
#pragma unroll
    for (int l = 0; l < 4; ++l) {
      int ci = (w * 4 + l) * 64 + lane;
      int kr = ci >> 4, kc = (ci & 15) ^ (kr & 7);
      gld16((char*)Ks[buf] + (w * 4 + l) * 1024,
            Kb + ((size_t)bh * Tn + k0 + kr) * DHn + kc * 8);
      int vr = ci >> 3, vc = (ci & 7) ^ (vr & 7);
      gld16((char*)Vs[buf] + (w * 4 + l) * 1024,
            Vt + ((size_t)bh * DHn + vr) * Tn + k0 + vc * 8);
    }
  };

  stage(0, 0);

  for (int kt = 0; kt <= kmax; ++kt) {
    __syncthreads();
    if (kt < kmax) stage((kt + 1) & 1, kt + 1);
    const bf16_t* ks = Ks[kt & 1];
    const bf16_t* vs = Vs[kt & 1];
    const bool actA = (kt <= iA);
    const int k0 = kt * 64;

    f32x4 saA[4] = {}, saB[4] = {};
    __builtin_amdgcn_s_setprio(1);
    if (actA) {
#pragma unroll
      for (int s = 0; s < 4; ++s) {
#pragma unroll
        for (int n = 0; n < 4; ++n) {
          bf16x8 bk = *(const bf16x8*)&ks[(n * 16 + q) * 128 + (((s * 4 + g) ^ (q & 7)) * 8)];
          saA[n] = __builtin_amdgcn_mfma_f32_16x16x32_bf16(aqA[s], bk, saA[n], 0, 0, 0);
          saB[n] = __builtin_amdgcn_mfma_f32_16x16x32_bf16(aqB[s], bk, saB[n], 0, 0, 0);
        }
      }
    } else {
#pragma unroll
      for (int s = 0; s < 4; ++s) {
#pragma unroll
        for (int n = 0; n < 4; ++n) {
          bf16x8 bk = *(const bf16x8*)&ks[(n * 16 + q) * 128 + (((s * 4 + g) ^ (q & 7)) * 8)];
          saB[n] = __builtin_amdgcn_mfma_f32_16x16x32_bf16(aqB[s], bk, saB[n], 0, 0, 0);
        }
      }
    }
    __builtin_amdgcn_s_setprio(0);

    bf16x8 paA[2], paB[2];
    auto softmax_p = [&](f32x4* sa, float* mst, float* lst, int itile,
                         bf16x8* pa, int qrow) {
      if (kt == itile) {
#pragma unroll
        for (int n = 0; n < 4; ++n)
#pragma unroll
          for (int j = 0; j < 4; ++j) {
            int kc = k0 + n * 16 + q;
            int qr = qrow + g * 4 + j;
            if (kc > qr) sa[n][j] = -1e30f;
          }
      }
      float mx[4];
#pragma unroll
      for (int j = 0; j < 4; ++j) {
        mx[j] = fmaxf(fmaxf(sa[0][j], sa[1][j]), fmaxf(sa[2][j], sa[3][j]));
#pragma unroll
        for (int off = 1; off < 16; off <<= 1)
          mx[j] = fmaxf(mx[j], __shfl_xor(mx[j], off, 16));
      }
      float ps[4][4], rsum[4];
#pragma unroll
      for (int j = 0; j < 4; ++j) rsum[j] = 0.0f;
      float mnew[4], corr[4];
#pragma unroll
      for (int j = 0; j < 4; ++j) {
        mnew[j] = fmaxf(mst[j], mx[j]);
        corr[j] = exp2f((mst[j] - mnew[j]) * LOG2E);
      }
#pragma unroll
      for (int n = 0; n < 4; ++n)
#pragma unroll
        for (int j = 0; j < 4; ++j) {
          ps[n][j] = exp2f((sa[n][j] - mnew[j]) * LOG2E);
          rsum[j] += ps[n][j];
        }
#pragma unroll
      for (int j = 0; j < 4; ++j) {
#pragma unroll
        for (int off = 1; off < 16; off <<= 1)
          rsum[j] += __shfl_xor(rsum[j], off, 16);
        lst[j] = lst[j] * corr[j] + rsum[j];
        mst[j] = mnew[j];
      }
#pragma unroll
      for (int n = 0; n < 4; ++n)
#pragma unroll
        for (int j = 0; j < 4; ++j)
          Ps[w][(g * 4 + j) * 72 + n * 16 + q] = (bf16_t)ps[n][j];
#pragma unroll
      for (int s2 = 0; s2 < 2; ++s2)
        pa[s2] = *(const bf16x8*)&Ps[w][q * 72 + s2 * 32 + g * 8];
      return corr;
    };

    float cA[4], cB[4];
    if (actA) {
      auto c = softmax_p(saA, mA, lA, iA, paA, iA * 64 + w * 16);
#pragma unroll
      for (int j = 0; j < 4; ++j) cA[j] = c[j];
#pragma unroll
      for (int n8 = 0; n8 < 8; ++n8)
#pragma unroll
        for (int j = 0; j < 4; ++j) oA[n8][j] *= cA[j];
    }
    {
      auto c = softmax_p(saB, mB, lB, iB, paB, iB * 64 + w * 16);
#pragma unroll
      for (int j = 0; j < 4; ++j) cB[j] = c[j];
#pragma unroll
      for (int n8 = 0; n8 < 8; ++n8)
#pragma unroll
        for (int j = 0; j < 4; ++j) oB[n8][j] *= cB[j];
    }

    __builtin_amdgcn_s_setprio(1);
    if (actA) {
#pragma unroll
      for (int s2 = 0; s2 < 2; ++s2)
#pragma unroll
        for (int n8 = 0; n8 < 8; ++n8) {
          bf16x8 bv = *(const bf16x8*)&vs[(n8 * 16 + q) * 64 + (((s2 * 4 + g) ^ (q & 7)) * 8)];
          oA[n8] = __builtin_amdgcn_mfma_f32_16x16x32_bf16(paA[s2], bv, oA[n8], 0, 0, 0);
          oB[n8] = __builtin_amdgcn_mfma_f32_16x16x32_bf16(paB[s2], bv, oB[n8], 0, 0, 0);
        }
    } else {
#pragma unroll
      for (int s2 = 0; s2 < 2; ++s2)
#pragma unroll
        for (int n8 = 0; n8 < 8; ++n8) {
          bf16x8 bv = *(const bf16x8*)&vs[(n8 * 16 + q) * 64 + (((s2 * 4 + g) ^ (q & 7)) * 8)];
          oB[n8] = __builtin_amdgcn_mfma_f32_16x16x32_bf16(paB[s2], bv, oB[n8], 0, 0, 0);
        }
    }
    __builtin_amdgcn_s_setprio(0);
  }

#pragma unroll
  for (int n8 = 0; n8 < 8; ++n8)
#pragma unroll
    for (int j = 0; j < 4; ++j) {
      int trA = iA * 64 + w * 16 + g * 4 + j;
      int trB = iB * 64 + w * 16 + g * 4 + j;
      Y[(size_t)(b * Tn + trA) * Dn + hh * DHn + n8 * 16 + q] =
          (bf16_t)(oA[n8][j] / lA[j]);
      Y[(size_t)(b * Tn + trB) * Dn + hh * DHn + n8 * 16 + q] =
          (bf16_t)(oB[n8][j] / lB[j]);
    }
}

// ---------------- launcher ----------------
// Liveness (stream-ordered):
//  h:    h1 -> y(attn out) -> h2 -> Pm0
//  bufA: Pq1 -> Pp0/Pp1 -> Pm1
//  bufB: Pq0 -> gv
//  wb:   attn_w(cvt) -> Qb -> proj_w(cvt) -> mlp_w(cvt)
//  dout: Kb+Vt scratch -> x1 -> final out
extern "C" void kernel_launch(void* const* d_in, const int* in_sizes, int n_in,
                              void* d_out, int out_size, void* d_ws, size_t ws_size,
                              hipStream_t stream) {
  const float* x      = (const float*)d_in[0];
  const float* n1w    = (const float*)d_in[1];
  const float* n2w    = (const float*)d_in[2];
  const float* attn_w = (const float*)d_in[3];
  const float* proj_w = (const float*)d_in[4];
  const float* gate_w = (const float*)d_in[5];
  const float* val_w  = (const float*)d_in[6];
  const float* mlp_w  = (const float*)d_in[7];

  char* ws = (char*)d_ws;
  bf16_t* h    = (bf16_t*)(ws);                  // 16.78MB
  bf16_t* bufA = (bf16_t*)(ws + 16777216);       // 50.3MB
  bf16_t* bufB = (bf16_t*)(ws + 67108864);       // 50.3MB
  bf16_t* wb   = (bf16_t*)(ws + 117440512);      // 25.2MB

  bf16_t* Pq0  = bufB;                 // qkv partial 0
  bf16_t* Pq1  = bufA;                 // qkv partial 1
  bf16_t* Qb   = wb;                   // 16.78MB (attn_w dead after qkv gemm)
  bf16_t* Kb   = (bf16_t*)d_out;       // d_out scratch lower 16.78MB
  bf16_t* Vt   = (bf16_t*)d_out + (size_t)32 * Tn * DHn;  // upper 16.78MB
  bf16_t* y    = h;
  bf16_t* Pp0  = bufA;                 // proj partial 0 (16.78MB)
  bf16_t* Pp1  = bufA + (size_t)BTn * Dn;  // proj partial 1
  bf16_t* gv   = bufB;                 // gate*val (Pq0 dead after rope)
  bf16_t* Pm0  = h;                    // mlp partial 0 (h2 dead after gemmgv)
  bf16_t* Pm1  = bufA;                 // mlp partial 1 (Pp dead after rms_fused)
  float*  out  = (float*)d_out;

  // 1) h1 = rmsnorm(x)
  rmsnorm_k<<<BTn, 256, 0, stream>>>(x, n1w, h);
  // 2) qkv partials (split-K=2, 768 blocks = 3 full generations)
  cvt_pad_k<<<(TD3 * Dn / 8 + 255) / 256, 256, 0, stream>>>(attn_w, wb, TD3, Dn, Dn, TD3 * Dn / 8);
  gemm_sk<<<768, 512, 0, stream>>>(h, wb, Pq0, Pq1, Dn, Dn / 2, TD3, BTn / 256);
  // 3) fused reduce+rope+split+V^T: Q->wb, K/Vt->d_out scratch
  rope_fused<<<dim3(Tn / 32, 32), 256, 0, stream>>>(Pq0, Pq1, Qb, Kb, Vt);
  // 4) attention -> y (=h)
  attn_k<<<dim3(16, 32), 256, 0, stream>>>(Qb, Kb, Vt, y);
  // 5) proj partials (split-K=2, 256 blocks full-chip)
  cvt_pad_k<<<(Dn * Dn / 8 + 255) / 256, 256, 0, stream>>>(proj_w, wb, Dn, Dn, Dn, Dn * Dn / 8);
  gemm_sk<<<256, 512, 0, stream>>>(y, wb, Pp0, Pp1, Dn, Dn / 2, Dn, BTn / 256);
  // 6) fused: x1 = x + Pp0 + Pp1 -> out(d_out) ; h2 = rmsnorm(x1) -> h
  rms_fused<<<BTn, 256, 0, stream>>>(x, Pp0, Pp1, n2w, out, h);
  // 7+8) gv = silu(h2 @ gate_w^T) * (h2 @ val_w^T)  -- fp32 weights direct
  gemmgv<<<(FGPn / 128) * (BTn / 256), 512, 0, stream>>>(h, gate_w, val_w, gv, Dn, FGPn, BTn / 256);
  // 9) mlp partials (split-K=2, 256 blocks)
  cvt_pad_k<<<(Dn * FGPn / 8 + 255) / 256, 256, 0, stream>>>(mlp_w, wb, Dn, FGn, FGPn, Dn * FGPn / 8);
  gemm_sk<<<256, 512, 0, stream>>>(gv, wb, Pm0, Pm1, FGPn, FGPn / 2, Dn, BTn / 256);
  // 10) out += Pm0 + Pm1
  reduce_k<<<BTn * Dn / 8 / 256, 256, 0, stream>>>(out, Pm0, Pm1);
}

// Round 19
// 709.293 us; speedup vs baseline: 1.0120x; 1.0120x over previous
//
#include <hip/hip_runtime.h>
#include <hip/hip_bf16.h>
#include <stdint.h>

typedef __bf16 bf16_t;
typedef __bf16 bf16x8 __attribute__((ext_vector_type(8)));
typedef float  f32x4  __attribute__((ext_vector_type(4)));

#define DEV __device__ __forceinline__

constexpr int   Bn = 2, Tn = 2048, Dn = 2048, Hn = 16, DHn = 128;
constexpr int   BTn = Bn * Tn;          // 4096 rows
constexpr int   TD3 = 3 * Dn;           // 6144
constexpr int   FGn = 5461, FGPn = 5504; // pad to 43*128 (688 blocks, %8==0)
constexpr float EPSf   = 1e-5f;
constexpr float LOG2E  = 1.4426950408889634f;
constexpr float ASCALE = 0.08838834764831845f;   // 1/sqrt(128)
constexpr float LN1E4  = 9.210340371976184f;     // ln(10000)

// async global->LDS, 16B per lane, wave-uniform LDS base (HW adds lane*16)
DEV void gld16(void* lds, const void* g) {
  __builtin_amdgcn_global_load_lds(
      (__attribute__((address_space(1))) void*)(void*)g,
      (__attribute__((address_space(3))) void*)lds, 16, 0, 0);
}

// inline-asm LDS read, ordered only by explicit s_waitcnt lgkmcnt(N)
DEV bf16x8 dsr128(const bf16_t* p) {
  bf16x8 r;
  asm volatile("ds_read_b128 %0, %1"
               : "=v"(r)
               : "v"((const __attribute__((address_space(3))) bf16_t*)p));
  return r;
}

// ---------------- RMSNorm (fp32 in -> bf16 out) ----------------
__global__ __launch_bounds__(256)
void rmsnorm_k(const float* __restrict__ x, const float* __restrict__ w,
               bf16_t* __restrict__ out) {
  const int row = blockIdx.x;
  const int tid = threadIdx.x;
  const float* xr = x + (size_t)row * Dn;
  float4 a = ((const float4*)xr)[tid * 2];
  float4 b = ((const float4*)xr)[tid * 2 + 1];
  float ss = a.x*a.x + a.y*a.y + a.z*a.z + a.w*a.w
           + b.x*b.x + b.y*b.y + b.z*b.z + b.w*b.w;
#pragma unroll
  for (int off = 32; off > 0; off >>= 1) ss += __shfl_xor(ss, off, 64);
  __shared__ float red[4];
  if ((tid & 63) == 0) red[tid >> 6] = ss;
  __syncthreads();
  float tot = red[0] + red[1] + red[2] + red[3];
  float rms = rsqrtf(tot * (1.0f / Dn) + EPSf);
  float4 wa = ((const float4*)w)[tid * 2];
  float4 wb = ((const float4*)w)[tid * 2 + 1];
  bf16x8 o;
  o[0] = (bf16_t)(a.x * rms * wa.x); o[1] = (bf16_t)(a.y * rms * wa.y);
  o[2] = (bf16_t)(a.z * rms * wa.z); o[3] = (bf16_t)(a.w * rms * wa.w);
  o[4] = (bf16_t)(b.x * rms * wb.x); o[5] = (bf16_t)(b.y * rms * wb.y);
  o[6] = (bf16_t)(b.z * rms * wb.z); o[7] = (bf16_t)(b.w * rms * wb.w);
  *(bf16x8*)&out[(size_t)row * Dn + tid * 8] = o;
}

// ------- fused: x1 = x + P0 + P1 (fp32 out) ; h = rmsnorm(x1)*w (bf16) ----
__global__ __launch_bounds__(256)
void rms_fused(const float* __restrict__ x, const bf16_t* __restrict__ P0,
               const bf16_t* __restrict__ P1, const float* __restrict__ w,
               float* __restrict__ out, bf16_t* __restrict__ h) {
  const int row = blockIdx.x;
  const int tid = threadIdx.x;
  const size_t base = (size_t)row * Dn + tid * 8;
  float4 a = ((const float4*)(x + base))[0];
  float4 b = ((const float4*)(x + base))[1];
  bf16x8 p0 = *(const bf16x8*)&P0[base];
  bf16x8 p1 = *(const bf16x8*)&P1[base];
  float v[8];
  v[0] = a.x + (float)p0[0] + (float)p1[0];
  v[1] = a.y + (float)p0[1] + (float)p1[1];
  v[2] = a.z + (float)p0[2] + (float)p1[2];
  v[3] = a.w + (float)p0[3] + (float)p1[3];
  v[4] = b.x + (float)p0[4] + (float)p1[4];
  v[5] = b.y + (float)p0[5] + (float)p1[5];
  v[6] = b.z + (float)p0[6] + (float)p1[6];
  v[7] = b.w + (float)p0[7] + (float)p1[7];
  float4 o0 = {v[0], v[1], v[2], v[3]};
  float4 o1 = {v[4], v[5], v[6], v[7]};
  ((float4*)(out + base))[0] = o0;
  ((float4*)(out + base))[1] = o1;
  float ss = 0.f;
#pragma unroll
  for (int k = 0; k < 8; ++k) ss += v[k] * v[k];
#pragma unroll
  for (int off = 32; off > 0; off >>= 1) ss += __shfl_xor(ss, off, 64);
  __shared__ float red[4];
  if ((tid & 63) == 0) red[tid >> 6] = ss;
  __syncthreads();
  float tot = red[0] + red[1] + red[2] + red[3];
  float rms = rsqrtf(tot * (1.0f / Dn) + EPSf);
  float4 wa = ((const float4*)w)[tid * 2];
  float4 wb = ((const float4*)w)[tid * 2 + 1];
  bf16x8 o;
  o[0] = (bf16_t)(v[0] * rms * wa.x); o[1] = (bf16_t)(v[1] * rms * wa.y);
  o[2] = (bf16_t)(v[2] * rms * wa.z); o[3] = (bf16_t)(v[3] * rms * wa.w);
  o[4] = (bf16_t)(v[4] * rms * wb.x); o[5] = (bf16_t)(v[5] * rms * wb.y);
  o[6] = (bf16_t)(v[6] * rms * wb.z); o[7] = (bf16_t)(v[7] * rms * wb.w);
  *(bf16x8*)&h[base] = o;
}

// ---------------- fp32 -> bf16 convert with zero padding ----------------
__global__ __launch_bounds__(256)
void cvt_pad_k(const float* __restrict__ src, bf16_t* __restrict__ dst,
               int srcR, int srcC, int dstC, int n8) {
  int i = blockIdx.x * 256 + threadIdx.x;
  if (i >= n8) return;
  long base = (long)i * 8;
  int r = (int)(base / dstC);
  int c = (int)(base % dstC);
  bf16x8 o;
#pragma unroll
  for (int k = 0; k < 8; ++k) {
    int cc = c + k;
    float v = (r < srcR && cc < srcC) ? src[(size_t)r * srcC + cc] : 0.0f;
    o[k] = (bf16_t)v;
  }
  *(bf16x8*)&dst[base] = o;
}

// ------------- reduce: out += P0 + P1 (mlp epilogue) ---------------------
__global__ __launch_bounds__(256)
void reduce_k(float* __restrict__ out, const bf16_t* __restrict__ P0,
              const bf16_t* __restrict__ P1) {
  int i = blockIdx.x * 256 + threadIdx.x;
  bf16x8 p0 = *(const bf16x8*)&P0[(size_t)i * 8];
  bf16x8 p1 = *(const bf16x8*)&P1[(size_t)i * 8];
  float4 o0 = ((const float4*)out)[i * 2];
  float4 o1 = ((const float4*)out)[i * 2 + 1];
  o0.x += (float)p0[0] + (float)p1[0];
  o0.y += (float)p0[1] + (float)p1[1];
  o0.z += (float)p0[2] + (float)p1[2];
  o0.w += (float)p0[3] + (float)p1[3];
  o1.x += (float)p0[4] + (float)p1[4];
  o1.y += (float)p0[5] + (float)p1[5];
  o1.z += (float)p0[6] + (float)p1[6];
  o1.w += (float)p0[7] + (float)p1[7];
  ((float4*)out)[i * 2]     = o0;
  ((float4*)out)[i * 2 + 1] = o1;
}

// -------- split-K=2 GEMM, BK=64 2-slot (best measured: ~5860 cyc/K64) ----
__global__ __launch_bounds__(512, 2)
void gemm_sk(const bf16_t* __restrict__ A, const bf16_t* __restrict__ W,
             bf16_t* __restrict__ P0, bf16_t* __restrict__ P1,
             int ldk, int klen, int ldc, int nby) {
  __shared__ __align__(128) bf16_t As[2][256 * 64];   // 2 x 32KB
  __shared__ __align__(128) bf16_t Bs[2][256 * 64];   // 2 x 32KB
  const int tid = threadIdx.x;
  const int lane = tid & 63, w = tid >> 6;
  const int wm = w >> 2, wn = w & 3;
  const int g = lane >> 4, q = lane & 15;

  const int nwg = gridDim.x;               // % 8 == 0
  const int cpx = nwg >> 3;
  const int nid = (blockIdx.x & 7) * cpx + (blockIdx.x >> 3);
  const int half = nwg >> 1;
  const int s   = nid / half;
  const int rem = nid % half;
  const int bx = rem / nby, by = rem % nby;
  const int row0 = by * 256, col0 = bx * 256;
  const int kofs = s * klen;
  bf16_t* P = s ? P1 : P0;

  f32x4 acc[8][4] = {};

  const bf16_t* Asrc[4];
  const bf16_t* Wsrc[4];
  int aoff[4];
#pragma unroll
  for (int i = 0; i < 4; ++i) {
    int ci = i * 512 + tid;
    int r  = ci >> 3;
    int cs = (ci & 7) ^ (r & 7);
    Asrc[i] = A + (size_t)(row0 + r) * ldk + kofs + cs * 8;
    Wsrc[i] = W + (size_t)(col0 + r) * ldk + kofs + cs * 8;
    aoff[i] = i * 8192 + w * 1024;
  }

  int offA[2][8], offB[2][4];
#pragma unroll
  for (int kk = 0; kk < 2; ++kk) {
#pragma unroll
    for (int m = 0; m < 8; ++m) {
      int r = wm * 128 + m * 16 + q;
      offA[kk][m] = r * 128 + (((kk * 4 + g) ^ (r & 7)) * 16);
    }
#pragma unroll
    for (int n = 0; n < 4; ++n) {
      int r = wn * 64 + n * 16 + q;
      offB[kk][n] = r * 128 + (((kk * 4 + g) ^ (r & 7)) * 16);
    }
  }

  const int NT = klen >> 6;
  auto stage = [&](int T, int h) {
    const int slot = T & 1;
    const size_t kk = (size_t)T * 64;
#pragma unroll
    for (int i = 0; i < 2; ++i) {
      int rd = h * 2 + i;
      gld16((char*)As[slot] + aoff[rd], Asrc[rd] + kk);
      gld16((char*)Bs[slot] + aoff[rd], Wsrc[rd] + kk);
    }
  };

  bf16x8 af[8], bfr[4];

  auto half_rd = [&](const char* as_, const char* bs_, int kk) {
#pragma unroll
    for (int m = 0; m < 8; ++m) af[m] = dsr128((const bf16_t*)(as_ + offA[kk][m]));
#pragma unroll
    for (int n = 0; n < 4; ++n) bfr[n] = dsr128((const bf16_t*)(bs_ + offB[kk][n]));
  };
  auto mfmas = [&]() {
    asm volatile("s_waitcnt lgkmcnt(0)" ::: "memory");
    __builtin_amdgcn_sched_barrier(0);
    __builtin_amdgcn_s_setprio(1);
#pragma unroll
    for (int m = 0; m < 8; ++m)
#pragma unroll
      for (int n = 0; n < 4; ++n)
        acc[m][n] = __builtin_amdgcn_mfma_f32_16x16x32_bf16(af[m], bfr[n], acc[m][n], 0, 0, 0);
    __builtin_amdgcn_s_setprio(0);
    __builtin_amdgcn_sched_barrier(0);
  };

  stage(0, 0); stage(0, 1);
  asm volatile("s_waitcnt vmcnt(0)" ::: "memory");
  asm volatile("s_barrier" ::: "memory");

  for (int T = 0; T < NT; ++T) {
    const char* as_ = (const char*)As[T & 1];
    const char* bs_ = (const char*)Bs[T & 1];
    const bool st = (T + 1 < NT);
    half_rd(as_, bs_, 0);
    if (st) stage(T + 1, 0);
    mfmas();
    half_rd(as_, bs_, 1);
    if (st) stage(T + 1, 1);
    mfmas();
    if (st) asm volatile("s_waitcnt vmcnt(0)" ::: "memory");
    asm volatile("s_barrier" ::: "memory");
  }

#pragma unroll
  for (int m = 0; m < 8; ++m)
#pragma unroll
    for (int n = 0; n < 4; ++n)
#pragma unroll
      for (int j = 0; j < 4; ++j) {
        int r = row0 + wm * 128 + m * 16 + g * 4 + j;
        int c = col0 + wn * 64 + n * 16 + q;
        P[(size_t)r * ldc + c] = (bf16_t)acc[m][n][j];
      }
}

// ------- fused gate+val dual GEMM, BK=64: Out = silu(A Wg^T)*(A Wv^T) -----
// (R14/R16 exact: bf16-staged weights, 164us, MfmaUtil 51%)
__global__ __launch_bounds__(512, 2)
void gemmgv(const bf16_t* __restrict__ A, const bf16_t* __restrict__ Wg,
            const bf16_t* __restrict__ Wv, bf16_t* __restrict__ Out,
            int K, int ldc, int nby) {
  __shared__ __align__(128) bf16_t As[2][256 * 64];   // 2 x 32KB
  __shared__ __align__(128) bf16_t Gs[2][128 * 64];   // 2 x 16KB
  __shared__ __align__(128) bf16_t Vs[2][128 * 64];   // 2 x 16KB
  const int tid = threadIdx.x;
  const int lane = tid & 63, w = tid >> 6;
  const int wm = w >> 2, wn = w & 3;
  const int g = lane >> 4, q = lane & 15;

  const int nwg = gridDim.x;                 // 688, % 8 == 0
  const int cpx = nwg >> 3;
  const int nid = (blockIdx.x & 7) * cpx + (blockIdx.x >> 3);
  const int bx = nid / nby, by = nid % nby;
  const int row0 = by * 256, col0 = bx * 128;

  f32x4 accg[8][2] = {}, accv[8][2] = {};

  const bf16_t* Asrc[4];
  int aoff[4];
#pragma unroll
  for (int i = 0; i < 4; ++i) {
    int ci = i * 512 + tid;
    int r  = ci >> 3;
    int cs = (ci & 7) ^ (r & 7);
    Asrc[i] = A + (size_t)(row0 + r) * K + cs * 8;
    aoff[i] = i * 8192 + w * 1024;
  }
  const bf16_t* Gsrc[2];
  const bf16_t* Vsrc[2];
  int boff[2];
#pragma unroll
  for (int i = 0; i < 2; ++i) {
    int ci = i * 512 + tid;
    int r  = ci >> 3;
    int cs = (ci & 7) ^ (r & 7);
    Gsrc[i] = Wg + (size_t)(col0 + r) * K + cs * 8;
    Vsrc[i] = Wv + (size_t)(col0 + r) * K + cs * 8;
    boff[i] = i * 8192 + w * 1024;
  }

  int offA[2][8], offB[2][2];
#pragma unroll
  for (int kk = 0; kk < 2; ++kk) {
#pragma unroll
    for (int m = 0; m < 8; ++m) {
      int r = wm * 128 + m * 16 + q;
      offA[kk][m] = r * 128 + (((kk * 4 + g) ^ (r & 7)) * 16);
    }
#pragma unroll
    for (int n = 0; n < 2; ++n) {
      int r = wn * 32 + n * 16 + q;
      offB[kk][n] = r * 128 + (((kk * 4 + g) ^ (r & 7)) * 16);
    }
  }

  const int NT = K >> 6;                 // 32
  auto stage = [&](int T, int h) {
    const int slot = T & 1;
    const size_t kk = (size_t)T * 64;
#pragma unroll
    for (int i = 0; i < 2; ++i) {
      int rd = h * 2 + i;
      gld16((char*)As[slot] + aoff[rd], Asrc[rd] + kk);
    }
    gld16((char*)Gs[slot] + boff[h], Gsrc[h] + kk);
    gld16((char*)Vs[slot] + boff[h], Vsrc[h] + kk);
  };

  bf16x8 af[8], bg[2], bv[2];

  auto half_rd = [&](const char* as_, const char* gs_, const char* vs_, int kk) {
#pragma unroll
    for (int m = 0; m < 8; ++m) af[m] = dsr128((const bf16_t*)(as_ + offA[kk][m]));
#pragma unroll
    for (int n = 0; n < 2; ++n) {
      bg[n] = dsr128((const bf16_t*)(gs_ + offB[kk][n]));
      bv[n] = dsr128((const bf16_t*)(vs_ + offB[kk][n]));
    }
  };
  auto mfmas = [&]() {
    asm volatile("s_waitcnt lgkmcnt(0)" ::: "memory");
    __builtin_amdgcn_sched_barrier(0);
    __builtin_amdgcn_s_setprio(1);
#pragma unroll
    for (int m = 0; m < 8; ++m)
#pragma unroll
      for (int n = 0; n < 2; ++n) {
        accg[m][n] = __builtin_amdgcn_mfma_f32_16x16x32_bf16(af[m], bg[n], accg[m][n], 0, 0, 0);
        accv[m][n] = __builtin_amdgcn_mfma_f32_16x16x32_bf16(af[m], bv[n], accv[m][n], 0, 0, 0);
      }
    __builtin_amdgcn_s_setprio(0);
    __builtin_amdgcn_sched_barrier(0);
  };

  stage(0, 0); stage(0, 1);
  asm volatile("s_waitcnt vmcnt(0)" ::: "memory");
  asm volatile("s_barrier" ::: "memory");

  for (int T = 0; T < NT; ++T) {
    const char* as_ = (const char*)As[T & 1];
    const char* gs_ = (const char*)Gs[T & 1];
    const char* vs_ = (const char*)Vs[T & 1];
    const bool st = (T + 1 < NT);
    half_rd(as_, gs_, vs_, 0);
    if (st) stage(T + 1, 0);
    mfmas();
    half_rd(as_, gs_, vs_, 1);
    if (st) stage(T + 1, 1);
    mfmas();
    if (st) asm volatile("s_waitcnt vmcnt(0)" ::: "memory");
    asm volatile("s_barrier" ::: "memory");
  }

#pragma unroll
  for (int m = 0; m < 8; ++m) {
#pragma unroll
    for (int n = 0; n < 2; ++n) {
#pragma unroll
      for (int j = 0; j < 4; ++j) {
        int r = row0 + wm * 128 + m * 16 + g * 4 + j;
        int c = col0 + wn * 32 + n * 16 + q;
        float gt = accg[m][n][j];
        float sg = gt / (1.0f + __expf(-gt));
        Out[(size_t)r * ldc + c] = (bf16_t)(sg * accv[m][n][j]);
      }
    }
  }
}

// -------- fused RoPE: reads qkv split-K partials (P0+P1), split + V^T ----
__global__ __launch_bounds__(256)
void rope_fused(const bf16_t* __restrict__ P0, const bf16_t* __restrict__ P1,
                bf16_t* __restrict__ Qb, bf16_t* __restrict__ Kb,
                bf16_t* __restrict__ Vt) {
  const int t0 = blockIdx.x * 32;
  const int bh = blockIdx.y;
  const int b = bh >> 4, hh = bh & 15;
  __shared__ bf16_t Vl[32][132];

#pragma unroll
  for (int it = 0; it < 2; ++it) {
    int task = threadIdx.x + it * 256;
    int tt = task >> 4, ck = task & 15, d0 = ck * 8;
    int tg = t0 + tt;
    const size_t rb = (size_t)(b * Tn + tg) * TD3 + hh * DHn + d0;
    bf16x8 q0 = *(const bf16x8*)&P0[rb];
    bf16x8 q1 = *(const bf16x8*)&P1[rb];
    bf16x8 k0 = *(const bf16x8*)&P0[rb + Dn];
    bf16x8 k1 = *(const bf16x8*)&P1[rb + Dn];
    bf16x8 v0 = *(const bf16x8*)&P0[rb + 2 * Dn];
    bf16x8 v1 = *(const bf16x8*)&P1[rb + 2 * Dn];
    bf16x8 qo, ko, vo;
#pragma unroll
    for (int p = 0; p < 4; ++p) {
      int jj = (d0 >> 1) + p;
      float fr = __expf(-((float)(2 * jj) / 128.0f) * LN1E4);
      float ang = (float)tg * fr;
      float cs = cosf(ang), sn = sinf(ang);
      float qe = (float)q0[2 * p] + (float)q1[2 * p];
      float qod = (float)q0[2 * p + 1] + (float)q1[2 * p + 1];
      float ke = (float)k0[2 * p] + (float)k1[2 * p];
      float kod = (float)k0[2 * p + 1] + (float)k1[2 * p + 1];
      qo[2 * p]     = (bf16_t)((qe * cs - qod * sn) * ASCALE);
      qo[2 * p + 1] = (bf16_t)((qod * cs + qe * sn) * ASCALE);
      ko[2 * p]     = (bf16_t)(ke * cs - kod * sn);
      ko[2 * p + 1] = (bf16_t)(kod * cs + ke * sn);
      vo[2 * p]     = (bf16_t)((float)v0[2 * p] + (float)v1[2 * p]);
      vo[2 * p + 1] = (bf16_t)((float)v0[2 * p + 1] + (float)v1[2 * p + 1]);
    }
    *(bf16x8*)&Qb[((size_t)bh * Tn + tg) * DHn + d0] = qo;
    *(bf16x8*)&Kb[((size_t)bh * Tn + tg) * DHn + d0] = ko;
    *(bf16x8*)&Vl[tt][d0] = vo;
  }
  __syncthreads();
#pragma unroll
  for (int it = 0; it < 2; ++it) {
    int task = threadIdx.x + it * 256;
    int dd = task >> 2, tc = (task & 3) * 8;
    bf16x8 ov;
#pragma unroll
    for (int i = 0; i < 8; ++i) ov[i] = Vl[tc + i][dd];
    *(bf16x8*)&Vt[((size_t)bh * DHn + dd) * Tn + t0 + tc] = ov;
  }
}

// ---------------- causal flash attention, paired q-tiles ----------------
__global__ __launch_bounds__(256, 2)
void attn_k(const bf16_t* __restrict__ Qb, const bf16_t* __restrict__ Kb,
            const bf16_t* __restrict__ Vt, bf16_t* __restrict__ Y) {
  const int orig = blockIdx.x + 16 * blockIdx.y;   // 512 blocks total
  const int nid  = (orig & 7) * 64 + (orig >> 3);  // XCD-chunked, bijective
  const int pi = nid & 15;
  const int bh = nid >> 4;
  const int b = bh >> 4, hh = bh & 15;
  const int tid = threadIdx.x, lane = tid & 63, w = tid >> 6;
  const int g = lane >> 4, q = lane & 15;
  const int iA = pi, iB = 31 - pi;
  const int kmax = iB;

  __shared__ bf16_t Ks[2][64 * 128];
  __shared__ bf16_t Vs[2][128 * 64];
  __shared__ bf16_t Ps[4][16 * 72];

  bf16x8 aqA[4], aqB[4];
  {
    const bf16_t* QrA = Qb + ((size_t)bh * Tn + iA * 64 + w * 16 + q) * DHn;
    const bf16_t* QrB = Qb + ((size_t)bh * Tn + iB * 64 + w * 16 + q) * DHn;
#pragma unroll
    for (int s = 0; s < 4; ++s) {
      aqA[s] = *(const bf16x8*)(QrA + s * 32 + g * 8);
      aqB[s] = *(const bf16x8*)(QrB + s * 32 + g * 8);
    }
  }

  f32x4 oA[8] = {}, oB[8] = {};
  float mA[4], lA[4], mB[4], lB[4];
#pragma unroll
  for (int j = 0; j < 4; ++j) {
    mA[j] = -__builtin_inff(); lA[j] = 0.0f;
    mB[j] = -__builtin_inff(); lB[j] = 0.0f;
  }

  auto stage = [&](int buf, int kt) {
    const int k0 = kt * 64;
#pragma unroll
    for (int l = 0; l < 4; ++l) {
      int ci = (w * 4 + l) * 64 + lane;
      int kr = ci >> 4, kc = (ci & 15) ^ (kr & 7);
      gld16((char*)Ks[buf] + (w * 4 + l) * 1024,
            Kb + ((size_t)bh * Tn + k0 + kr) * DHn + kc * 8);
      int vr = ci >> 3, vc = (ci & 7) ^ (vr & 7);
      gld16((char*)Vs[buf] + (w * 4 + l) * 1024,
            Vt + ((size_t)bh * DHn + vr) * Tn + k0 + vc * 8);
    }
  };

  stage(0, 0);

  for (int kt = 0; kt <= kmax; ++kt) {
    __syncthreads();
    if (kt < kmax) stage((kt + 1) & 1, kt + 1);
    const bf16_t* ks = Ks[kt & 1];
    const bf16_t* vs = Vs[kt & 1];
    const bool actA = (kt <= iA);
    const int k0 = kt * 64;

    f32x4 saA[4] = {}, saB[4] = {};
    __builtin_amdgcn_s_setprio(1);
    if (actA) {
#pragma unroll
      for (int s = 0; s < 4; ++s) {
#pragma unroll
        for (int n = 0; n < 4; ++n) {
          bf16x8 bk = *(const bf16x8*)&ks[(n * 16 + q) * 128 + (((s * 4 + g) ^ (q & 7)) * 8)];
          saA[n] = __builtin_amdgcn_mfma_f32_16x16x32_bf16(aqA[s], bk, saA[n], 0, 0, 0);
          saB[n] = __builtin_amdgcn_mfma_f32_16x16x32_bf16(aqB[s], bk, saB[n], 0, 0, 0);
        }
      }
    } else {
#pragma unroll
      for (int s = 0; s < 4; ++s) {
#pragma unroll
        for (int n = 0; n < 4; ++n) {
          bf16x8 bk = *(const bf16x8*)&ks[(n * 16 + q) * 128 + (((s * 4 + g) ^ (q & 7)) * 8)];
          saB[n] = __builtin_amdgcn_mfma_f32_16x16x32_bf16(aqB[s], bk, saB[n], 0, 0, 0);
        }
      }
    }
    __builtin_amdgcn_s_setprio(0);

    bf16x8 paA[2], paB[2];
    auto softmax_p = [&](f32x4* sa, float* mst, float* lst, int itile,
                         bf16x8* pa, int qrow) {
      if (kt == itile) {
#pragma unroll
        for (int n = 0; n < 4; ++n)
#pragma unroll
          for (int j = 0; j < 4; ++j) {
            int kc = k0 + n * 16 + q;
            int qr = qrow + g * 4 + j;
            if (kc > qr) sa[n][j] = -1e30f;
          }
      }
      float mx[4];
#pragma unroll
      for (int j = 0; j < 4; ++j) {
        mx[j] = fmaxf(fmaxf(sa[0][j], sa[1][j]), fmaxf(sa[2][j], sa[3][j]));
#pragma unroll
        for (int off = 1; off < 16; off <<= 1)
          mx[j] = fmaxf(mx[j], __shfl_xor(mx[j], off, 16));
      }
      float ps[4][4], rsum[4];
#pragma unroll
      for (int j = 0; j < 4; ++j) rsum[j] = 0.0f;
      float mnew[4], corr[4];
#pragma unroll
      for (int j = 0; j < 4; ++j) {
        mnew[j] = fmaxf(mst[j], mx[j]);
        corr[j] = exp2f((mst[j] - mnew[j]) * LOG2E);
      }
#pragma unroll
      for (int n = 0; n < 4; ++n)
#pragma unroll
        for (int j = 0; j < 4; ++j) {
          ps[n][j] = exp2f((sa[n][j] - mnew[j]) * LOG2E);
          rsum[j] += ps[n][j];
        }
#pragma unroll
      for (int j = 0; j < 4; ++j) {
#pragma unroll
        for (int off = 1; off < 16; off <<= 1)
          rsum[j] += __shfl_xor(rsum[j], off, 16);
        lst[j] = lst[j] * corr[j] + rsum[j];
        mst[j] = mnew[j];
      }
#pragma unroll
      for (int n = 0; n < 4; ++n)
#pragma unroll
        for (int j = 0; j < 4; ++j)
          Ps[w][(g * 4 + j) * 72 + n * 16 + q] = (bf16_t)ps[n][j];
#pragma unroll
      for (int s2 = 0; s2 < 2; ++s2)
        pa[s2] = *(const bf16x8*)&Ps[w][q * 72 + s2 * 32 + g * 8];
      return corr;
    };

    float cA[4], cB[4];
    if (actA) {
      auto c = softmax_p(saA, mA, lA, iA, paA, iA * 64 + w * 16);
#pragma unroll
      for (int j = 0; j < 4; ++j) cA[j] = c[j];
#pragma unroll
      for (int n8 = 0; n8 < 8; ++n8)
#pragma unroll
        for (int j = 0; j < 4; ++j) oA[n8][j] *= cA[j];
    }
    {
      auto c = softmax_p(saB, mB, lB, iB, paB, iB * 64 + w * 16);
#pragma unroll
      for (int j = 0; j < 4; ++j) cB[j] = c[j];
#pragma unroll
      for (int n8 = 0; n8 < 8; ++n8)
#pragma unroll
        for (int j = 0; j < 4; ++j) oB[n8][j] *= cB[j];
    }

    __builtin_amdgcn_s_setprio(1);
    if (actA) {
#pragma unroll
      for (int s2 = 0; s2 < 2; ++s2)
#pragma unroll
        for (int n8 = 0; n8 < 8; ++n8) {
          bf16x8 bv = *(const bf16x8*)&vs[(n8 * 16 + q) * 64 + (((s2 * 4 + g) ^ (q & 7)) * 8)];
          oA[n8] = __builtin_amdgcn_mfma_f32_16x16x32_bf16(paA[s2], bv, oA[n8], 0, 0, 0);
          oB[n8] = __builtin_amdgcn_mfma_f32_16x16x32_bf16(paB[s2], bv, oB[n8], 0, 0, 0);
        }
    } else {
#pragma unroll
      for (int s2 = 0; s2 < 2; ++s2)
#pragma unroll
        for (int n8 = 0; n8 < 8; ++n8) {
          bf16x8 bv = *(const bf16x8*)&vs[(n8 * 16 + q) * 64 + (((s2 * 4 + g) ^ (q & 7)) * 8)];
          oB[n8] = __builtin_amdgcn_mfma_f32_16x16x32_bf16(paB[s2], bv, oB[n8], 0, 0, 0);
        }
    }
    __builtin_amdgcn_s_setprio(0);
  }

#pragma unroll
  for (int n8 = 0; n8 < 8; ++n8)
#pragma unroll
    for (int j = 0; j < 4; ++j) {
      int trA = iA * 64 + w * 16 + g * 4 + j;
      int trB = iB * 64 + w * 16 + g * 4 + j;
      Y[(size_t)(b * Tn + trA) * Dn + hh * DHn + n8 * 16 + q] =
          (bf16_t)(oA[n8][j] / lA[j]);
      Y[(size_t)(b * Tn + trB) * Dn + hh * DHn + n8 * 16 + q] =
          (bf16_t)(oB[n8][j] / lB[j]);
    }
}

// ---------------- launcher ----------------
// Liveness (stream-ordered):
//  h:    h1 -> y(attn out) -> h2 -> Pm0
//  bufA: Pq1 -> Pp0/Pp1 -> wbV(val weights) -> Pm1
//  bufB: Pq0 -> gv
//  wb:   attn_w(cvt) -> Qb -> proj_w(cvt) -> gate_w(cvt) -> mlp_w(cvt)
//  dout: Kb+Vt scratch -> x1 -> final out
extern "C" void kernel_launch(void* const* d_in, const int* in_sizes, int n_in,
                              void* d_out, int out_size, void* d_ws, size_t ws_size,
                              hipStream_t stream) {
  const float* x      = (const float*)d_in[0];
  const float* n1w    = (const float*)d_in[1];
  const float* n2w    = (const float*)d_in[2];
  const float* attn_w = (const float*)d_in[3];
  const float* proj_w = (const float*)d_in[4];
  const float* gate_w = (const float*)d_in[5];
  const float* val_w  = (const float*)d_in[6];
  const float* mlp_w  = (const float*)d_in[7];

  char* ws = (char*)d_ws;
  bf16_t* h    = (bf16_t*)(ws);                  // 16.78MB
  bf16_t* bufA = (bf16_t*)(ws + 16777216);       // 50.3MB
  bf16_t* bufB = (bf16_t*)(ws + 67108864);       // 50.3MB
  bf16_t* wb   = (bf16_t*)(ws + 117440512);      // 25.2MB

  bf16_t* Pq0  = bufB;                 // qkv partial 0
  bf16_t* Pq1  = bufA;                 // qkv partial 1
  bf16_t* Qb   = wb;                   // 16.78MB (attn_w dead after qkv gemm)
  bf16_t* Kb   = (bf16_t*)d_out;       // d_out scratch lower 16.78MB
  bf16_t* Vt   = (bf16_t*)d_out + (size_t)32 * Tn * DHn;  // upper 16.78MB
  bf16_t* y    = h;
  bf16_t* Pp0  = bufA;                 // proj partial 0 (16.78MB)
  bf16_t* Pp1  = bufA + (size_t)BTn * Dn;  // proj partial 1
  bf16_t* wbV  = bufA;                 // val weights (Pp dead after rms_fused)
  bf16_t* gv   = bufB;                 // gate*val (Pq0 dead after rope)
  bf16_t* Pm0  = h;                    // mlp partial 0 (h2 dead after gemmgv)
  bf16_t* Pm1  = bufA;                 // mlp partial 1 (wbV dead after gemmgv)
  float*  out  = (float*)d_out;

  // 1) h1 = rmsnorm(x)
  rmsnorm_k<<<BTn, 256, 0, stream>>>(x, n1w, h);
  // 2) qkv partials (split-K=2, 768 blocks = 3 full generations)
  cvt_pad_k<<<(TD3 * Dn / 8 + 255) / 256, 256, 0, stream>>>(attn_w, wb, TD3, Dn, Dn, TD3 * Dn / 8);
  gemm_sk<<<768, 512, 0, stream>>>(h, wb, Pq0, Pq1, Dn, Dn / 2, TD3, BTn / 256);
  // 3) fused reduce+rope+split+V^T: Q->wb, K/Vt->d_out scratch
  rope_fused<<<dim3(Tn / 32, 32), 256, 0, stream>>>(Pq0, Pq1, Qb, Kb, Vt);
  // 4) attention -> y (=h)
  attn_k<<<dim3(16, 32), 256, 0, stream>>>(Qb, Kb, Vt, y);
  // 5) proj partials (split-K=2, 256 blocks full-chip)
  cvt_pad_k<<<(Dn * Dn / 8 + 255) / 256, 256, 0, stream>>>(proj_w, wb, Dn, Dn, Dn, Dn * Dn / 8);
  gemm_sk<<<256, 512, 0, stream>>>(y, wb, Pp0, Pp1, Dn, Dn / 2, Dn, BTn / 256);
  // 6) fused: x1 = x + Pp0 + Pp1 -> out(d_out) ; h2 = rmsnorm(x1) -> h
  rms_fused<<<BTn, 256, 0, stream>>>(x, Pp0, Pp1, n2w, out, h);
  // 7+8) gv = silu(h2 @ gate_w^T) * (h2 @ val_w^T)  (bf16-staged weights)
  cvt_pad_k<<<(FGPn * Dn / 8 + 255) / 256, 256, 0, stream>>>(gate_w, wb, FGn, Dn, Dn, FGPn * Dn / 8);
  cvt_pad_k<<<(FGPn * Dn / 8 + 255) / 256, 256, 0, stream>>>(val_w, wbV, FGn, Dn, Dn, FGPn * Dn / 8);
  gemmgv<<<(FGPn / 128) * (BTn / 256), 512, 0, stream>>>(h, wb, wbV, gv, Dn, FGPn, BTn / 256);
  // 9) mlp partials (split-K=2, 256 blocks)
  cvt_pad_k<<<(Dn * FGPn / 8 + 255) / 256, 256, 0, stream>>>(mlp_w, wb, Dn, FGn, FGPn, Dn * FGPn / 8);
  gemm_sk<<<256, 512, 0, stream>>>(gv, wb, Pm0, Pm1, FGPn, FGPn / 2, Dn, BTn / 256);
  // 10) out += Pm0 + Pm1
  reduce_k<<<BTn * Dn / 8 / 256, 256, 0, stream>>>(out, Pm0, Pm1);
}